// Round 13
// baseline (151.850 us; speedup 1.0000x reference)
//
#include <hip/hip_runtime.h>

// ---------------------------------------------------------------------------
// MalConv fused: GEMM M=16000, K=4000, N=256 (W1||W2 col-interleaved) in bf16
// MFMA 16x16x32, lane-local GLU+relu+segmented-max epilogue, then tiny FC.
//
// Round-15 == round-6 unchanged (13th consecutive infra failure; structure
// frozen pending first bench):
//  * Bblk columns interleaved: 32-col group = 16 W1 cols + their 16 paired
//    W2 cols -> GLU pairs are lane-local (acc[mi][2p] / acc[mi][2p+1]);
//    epilogue wave-local, no LDS exchange, no barrier.
//  * 1000 blocks x 64 threads (1 independent wave), tile 64M x 64N
//    (acc[4][4]); B L2 traffic 500 MB ~ 15 us, MFMA floor ~ 4 us,
//    A LDS-gather ~ 320 cyc/CU/step -> jointly L2/LDS-bound ~300 cyc/step.
//  * 1 wave/SIMD baseline -> latency hidden by ILP: B (global, L2-resident)
//    and A (LDS gather) run DEPTH-2 register pipelines (600 cyc slack vs
//    ~300 cyc latency); x index loads depth-3. Tail clamps indices
//    (redundant reload of last tile) instead of branching.
//  * XCD-chunked block remap: the 4 nq waves of an m-tile sit 8 apart in
//    blockIdx -> same XCD -> x and Bblk L2 reuse.
// ---------------------------------------------------------------------------

typedef __attribute__((ext_vector_type(8))) short short8;
typedef __attribute__((ext_vector_type(4))) float f32x4;

__device__ __forceinline__ unsigned short f2b(float f) {
    union { float f; unsigned u; } un;
    un.f = f;
    unsigned u = un.u;
    return (unsigned short)((u + 0x7FFFu + ((u >> 16) & 1u)) >> 16);  // RNE
}

#define KT_COUNT 125                              // K = 4000 = 125 * 32
#define WS_BBLK_BYTES (KT_COUNT * 256 * 32 * 2)   // 2,048,000 B bf16 weights
#define WS_MWS_OFF WS_BBLK_BYTES                  // 8*128 f32 max accumulator

// Pack W1,W2 (fp32 [128][8][500]) -> bf16 Bblk[kt][c][g*8+ch] with
// INTERLEAVED columns: c = grp*32 + s; s<16 -> W1[grp*16+s], s>=16 ->
// W2[grp*16+s-16]. (kt,g) -> k = kt*4+g. One uint4 per thread, coalesced
// writes. Also zero-inits the m_ws max accumulator.
__global__ __launch_bounds__(256) void prep_weights(
        const float* __restrict__ W1, const float* __restrict__ W2,
        unsigned short* __restrict__ Bblk, float* __restrict__ m_ws) {
    int u   = blockIdx.x * 256 + threadIdx.x;     // 0 .. 127,999 (uint4 idx)
    int kt  = u >> 10;                            // /1024
    int rem = u & 1023;
    int c   = rem >> 2;                           // interleaved col 0..255
    int g   = rem & 3;
    int k   = kt * 4 + g;                         // 0..499
    int grp = c >> 5, s = c & 31;
    const float* W = (s < 16) ? W1 : W2;
    int oo = grp * 16 + (s & 15);                 // 0..127
    unsigned short v[8];
#pragma unroll
    for (int ch = 0; ch < 8; ++ch) v[ch] = f2b(W[oo * 4000 + ch * 500 + k]);
    uint4 pack;
    pack.x = (unsigned)v[0] | ((unsigned)v[1] << 16);
    pack.y = (unsigned)v[2] | ((unsigned)v[3] << 16);
    pack.z = (unsigned)v[4] | ((unsigned)v[5] << 16);
    pack.w = (unsigned)v[6] | ((unsigned)v[7] << 16);
    *(uint4*)&Bblk[u * 8] = pack;
    if (blockIdx.x < 4) m_ws[blockIdx.x * 256 + threadIdx.x] = 0.f;
}

// Main fused kernel: 1000 blocks x 64 threads (one wave). Work item
// w = mt*4 + nq: rows mt*64..+63, interleaved cols nq*64..+63.
__global__ __launch_bounds__(64, 2) void malconv_main(
        const int* __restrict__ x, const float* __restrict__ emb,
        const float* __restrict__ b1, const float* __restrict__ b2,
        const unsigned short* __restrict__ Bblk, float* __restrict__ m_ws) {
    __shared__ __align__(16) unsigned short embb[257 * 8];     // bf16 emb rows

    const int t = threadIdx.x;
    for (int e = t; e < 257 * 8; e += 64) embb[e] = f2b(emb[e]);

    // XCD-chunked remap: the 4 nq waves of an m-tile are 8 apart in
    // blockIdx -> same XCD under round-robin dispatch -> x/Bblk L2 reuse.
    const int w  = (blockIdx.x & 7) * 125 + (blockIdx.x >> 3);
    const int mt = w >> 2, nq = w & 3;
    const int m0 = mt * 64;

    const int quad = t >> 4, l16 = t & 15;

    // B fragment base: interleaved col = nq*64 + ni*16 + l16, 32 shorts/col
    // per kt, k-group = quad.
    const unsigned short* bbase = Bblk + (nq * 64 + l16) * 32 + quad * 8;

    // per-lane x pointers: row m0 + mi*16 + l16, position kt*4 + quad.
    const int* xr = x + (m0 + l16) * 500 + quad;   // + mi*8000 per mi

    f32x4 acc[4][4];
#pragma unroll
    for (int mi = 0; mi < 4; ++mi)
#pragma unroll
        for (int ni = 0; ni < 4; ++ni) {
            f32x4 z = {0.f, 0.f, 0.f, 0.f};
            acc[mi][ni] = z;
        }

    __syncthreads();  // embb ready (single wave; just an lgkm fence)

    // ---- pipeline preamble ----
    // A stages: acur=A@0, anx1=A@1 (gathered now); x regs xA=x@2, xB=x@3,
    // xC=x@4 (in flight). B stages: bcur=B@0, bnx1=B@1.
    short8 acur[4], anx1[4], anx2[4];
    int xA[4], xB[4], xC[4];
#pragma unroll
    for (int mi = 0; mi < 4; ++mi) {
        int v0 = xr[mi * 8000 + 0];
        int v1 = xr[mi * 8000 + 4];
        acur[mi] = *(const short8*)&embb[v0 * 8];
        anx1[mi] = *(const short8*)&embb[v1 * 8];
        xA[mi] = xr[mi * 8000 + 8];
        xB[mi] = xr[mi * 8000 + 12];
        xC[mi] = xr[mi * 8000 + 16];
    }
    short8 bcur[4], bnx1[4], bnx2[4];
#pragma unroll
    for (int ni = 0; ni < 4; ++ni) {
        bcur[ni] = *(const short8*)(bbase + ni * 512);
        bnx1[ni] = *(const short8*)(bbase + 8192 + ni * 512);
    }

    for (int kt = 0; kt < KT_COUNT; ++kt) {
        // issue B@kt+2 (global, L2-resident; clamped redundant reload at tail)
        const int ktb = (kt + 2 < KT_COUNT) ? kt + 2 : KT_COUNT - 1;
#pragma unroll
        for (int ni = 0; ni < 4; ++ni)
            bnx2[ni] = *(const short8*)(bbase + ktb * 8192 + ni * 512);
        // issue A gather @kt+2 (LDS; xA holds x@kt+2)
#pragma unroll
        for (int mi = 0; mi < 4; ++mi)
            anx2[mi] = *(const short8*)&embb[xA[mi] * 8];
        // x shift: load x@kt+5 (3 iters of slack; clamped at tail)
        const int ktx = (kt + 5 < KT_COUNT) ? kt + 5 : KT_COUNT - 1;
#pragma unroll
        for (int mi = 0; mi < 4; ++mi) {
            xA[mi] = xB[mi];
            xB[mi] = xC[mi];
            xC[mi] = xr[mi * 8000 + ktx * 4];
        }
        // MFMA: 16 independent accumulations on A@kt, B@kt
#pragma unroll
        for (int mi = 0; mi < 4; ++mi)
#pragma unroll
            for (int ni = 0; ni < 4; ++ni)
                acc[mi][ni] = __builtin_amdgcn_mfma_f32_16x16x32_bf16(
                    acur[mi], bcur[ni], acc[mi][ni], 0, 0, 0);
        // rotate stages
#pragma unroll
        for (int mi = 0; mi < 4; ++mi) { acur[mi] = anx1[mi]; anx1[mi] = anx2[mi]; }
#pragma unroll
        for (int ni = 0; ni < 4; ++ni) { bcur[ni] = bnx1[ni]; bnx1[ni] = bnx2[ni]; }
    }

    // ---- wave-local epilogue: GLU + relu + segmented max ----
    // pair p: g1 = acc[mi][2p] (W1 out j), g2 = acc[mi][2p+1] (W2 out j),
    // j = nq*32 + p*16 + l16.
    const int b0 = m0 / 2000;
    const int bsplit = (b0 + 1) * 2000;           // first patch of batch b0+1
    const bool crosses = (m0 + 63) >= bsplit;
#pragma unroll
    for (int p = 0; p < 2; ++p) {
        const int j = nq * 32 + p * 16 + l16;
        const float bb1 = b1[j], bb2 = b2[j];
        float mx0 = 0.f, mx1 = 0.f;               // h >= 0 always
#pragma unroll
        for (int mi = 0; mi < 4; ++mi)
#pragma unroll
            for (int r = 0; r < 4; ++r) {
                int row = m0 + mi * 16 + quad * 4 + r;
                float g1 = acc[mi][2 * p][r] + bb1;
                float g2 = acc[mi][2 * p + 1][r] + bb2;
                float h = fmaxf(g1 / (1.f + __expf(-g2)), 0.f);
                if (row >= bsplit) mx1 = fmaxf(mx1, h);
                else               mx0 = fmaxf(mx0, h);
            }
        // reduce over quad (lanes with same l16)
        mx0 = fmaxf(mx0, __shfl_xor(mx0, 16));
        mx0 = fmaxf(mx0, __shfl_xor(mx0, 32));
        mx1 = fmaxf(mx1, __shfl_xor(mx1, 16));
        mx1 = fmaxf(mx1, __shfl_xor(mx1, 32));
        if (quad == 0) {
            // nonneg floats: int compare == float compare
            atomicMax((int*)&m_ws[b0 * 128 + j], __float_as_int(mx0));
            if (crosses)
                atomicMax((int*)&m_ws[(b0 + 1) * 128 + j], __float_as_int(mx1));
        }
    }
}

// out[b][j] = sum_o m_ws[b][o] * fcW[j][o] + fcb[j]   (16 outputs)
__global__ void fc_kernel(const float* __restrict__ m_ws,
                          const float* __restrict__ fcW,
                          const float* __restrict__ fcb,
                          float* __restrict__ out) {
    int t = threadIdx.x;
    if (t < 16) {
        int b = t >> 1, j = t & 1;
        float s = 0.f;
        for (int o = 0; o < 128; ++o) s += m_ws[b * 128 + o] * fcW[j * 128 + o];
        out[t] = s + fcb[j];
    }
}

extern "C" void kernel_launch(void* const* d_in, const int* in_sizes, int n_in,
                              void* d_out, int out_size, void* d_ws, size_t ws_size,
                              hipStream_t stream) {
    const int*   x   = (const int*)d_in[0];     // [8, 1e6] values 0..256
    const float* emb = (const float*)d_in[1];   // [257, 8]
    const float* W1  = (const float*)d_in[2];   // [128, 8, 500]
    const float* b1  = (const float*)d_in[3];   // [128]
    const float* W2  = (const float*)d_in[4];   // [128, 8, 500]
    const float* b2  = (const float*)d_in[5];   // [128]
    const float* fcW = (const float*)d_in[6];   // [2, 128]
    const float* fcb = (const float*)d_in[7];   // [2]
    float* out = (float*)d_out;                 // [8, 2]

    unsigned short* Bblk = (unsigned short*)d_ws;
    float* m_ws = (float*)((char*)d_ws + WS_MWS_OFF);

    prep_weights<<<500, 256, 0, stream>>>(W1, W2, Bblk, m_ws);
    malconv_main<<<1000, 64, 0, stream>>>(x, emb, b1, b2, Bblk, m_ws);
    fc_kernel<<<1, 64, 0, stream>>>(m_ws, fcW, fcb, out);
}